// Round 3
// baseline (468.754 us; speedup 1.0000x reference)
//
#include <hip/hip_runtime.h>
#include <math.h>

#define NTOK 8192
#define NPG  512
#define MNEI 32
#define DM   256
#define DE   128
#define NH   8

// workspace offsets (in floats)
#define OFF_WCAT  0u          // 256*272   [k][272] : cols 0..7 qa, 8..15 ka, 16..271 v
#define OFF_BCAT  69632u      // 272
#define OFF_WEF   69904u      // 8*128  [h][r]
#define OFF_BEF   70928u      // 8
#define OFF_FLAG  70936u      // 1 int (pad to 70944)
#define OFF_QA    70944u      // 8192*8
#define OFF_KA    136480u     // 8192*8
#define OFF_GATE  202016u     // 8192
#define OFF_VW    210208u     // 8192*256
#define OFF_PROJ  2307360u    // 8192*3
#define OFF_VMAT  2331936u    // 16*9
#define OFF_CEN   2332080u    // 16*3
#define OFF_HCAT  2332128u    // 8192*384

#define OUT_GEO_OFF 2097152   // 8192*256

__device__ __forceinline__ void fma4x4(const float4 a, const float4 w, float4* acc) {
    acc[0].x += a.x*w.x; acc[0].y += a.x*w.y; acc[0].z += a.x*w.z; acc[0].w += a.x*w.w;
    acc[1].x += a.y*w.x; acc[1].y += a.y*w.y; acc[1].z += a.y*w.z; acc[1].w += a.y*w.w;
    acc[2].x += a.z*w.x; acc[2].y += a.z*w.y; acc[2].z += a.z*w.z; acc[2].w += a.z*w.w;
    acc[3].x += a.w*w.x; acc[3].y += a.w*w.y; acc[3].z += a.w*w.z; acc[3].w += a.w*w.w;
}

__device__ __forceinline__ float dot4(const float4 a, const float4 b) {
    return a.x*b.x + a.y*b.y + a.z*b.z + a.w*b.w;
}

// ---------------- Kernel 1: weight folding + mask layout detection ----------
__global__ __launch_bounds__(256) void k_fold(
    const float* __restrict__ Wqkv, const float* __restrict__ bqkv,
    const float* __restrict__ Wqkve, const float* __restrict__ bqkve,
    const float* __restrict__ w_attn, const float* __restrict__ w_edge,
    const int* __restrict__ maskp, float* __restrict__ ws)
{
    int t = threadIdx.x;
    if (blockIdx.x == 0) {
        __shared__ int sbad, sflt;
        if (t == 0) { sbad = 0; sflt = 0; }
        __syncthreads();
        int bad = 0, flt = 0;
        for (int i = 0; i < 256; i++) {
            unsigned int w = (unsigned int)maskp[i*256 + t];
            if (w > 1u) bad = 1;
            if (w == 0x3F800000u) flt = 1;
        }
        if (bad) atomicOr(&sbad, 1);
        if (flt) atomicOr(&sflt, 1);
        __syncthreads();
        if (t == 0) {
            int f = sflt ? 2 : (sbad ? 1 : 0);
            ((int*)(ws + OFF_FLAG))[0] = f;
        }
        return;
    }
    int gid = (blockIdx.x - 1) * 256 + t;
    if (gid < 69632) {
        int r = gid / 272, c = gid % 272;
        float val;
        if (c < 16) {
            int h = c & 7; int off = (c < 8) ? 0 : 256;
            float s = 0.f;
            for (int d = 0; d < 32; d++) s += Wqkv[r*768 + off + h*32 + d] * w_attn[d];
            val = s;
        } else {
            val = Wqkv[r*768 + 512 + (c - 16)];
        }
        ws[OFF_WCAT + gid] = val;
    } else if (gid < 69632 + 272) {
        int c = gid - 69632;
        float val;
        if (c < 16) {
            int h = c & 7; int off = (c < 8) ? 0 : 256;
            float s = 0.f;
            for (int d = 0; d < 32; d++) s += bqkv[off + h*32 + d] * w_attn[d];
            val = s;
        } else {
            val = bqkv[512 + (c - 16)];
        }
        ws[OFF_BCAT + c] = val;
    } else if (gid < 69904 + 1024) {
        int i = gid - 69904;
        int h = i >> 7, r = i & 127;
        float s = 0.f;
        for (int e = 0; e < 16; e++) s += Wqkve[r*256 + h*16 + e] * w_edge[e];
        ws[OFF_WEF + i] = s;
    } else if (gid < 70928 + 8) {
        int h = gid - 70928;
        float s = 0.f;
        for (int e = 0; e < 16; e++) s += bqkve[h*16 + e] * w_edge[e];
        ws[OFF_BEF + h] = s;
    }
}

// ---------------- Kernel 2: token LN + gate + [qa|ka|v] register-tiled GEMM
__global__ __launch_bounds__(320) void k_tokprep(
    const float* __restrict__ tok, const float* __restrict__ ln_g,
    const float* __restrict__ ln_b, const float* __restrict__ Wgate,
    const float* __restrict__ bgate, float* __restrict__ ws)
{
    __shared__ __align__(16) float sln[256 * 20];
    int t = threadIdx.x;
    int tok0 = blockIdx.x * 16;

    for (int idx = t; idx < 4096; idx += 320) {
        int tt = idx >> 8, k = idx & 255;
        sln[k*20 + tt] = tok[(size_t)(tok0 + tt) * 256 + k];
    }
    __syncthreads();

    int wave = t >> 6, lane = t & 63;
    if (wave < 4) {
        for (int rr = 0; rr < 4; rr++) {
            int tt = wave * 4 + rr;
            float s = 0.f, gdot = 0.f;
            float xs[4];
            for (int q = 0; q < 4; q++) {
                int k = lane + 64*q;
                float x = sln[k*20 + tt];
                xs[q] = x; s += x; gdot += x * Wgate[k];
            }
            for (int m = 32; m >= 1; m >>= 1) { s += __shfl_xor(s,m,64); gdot += __shfl_xor(gdot,m,64); }
            float mu = s * (1.0f/256.0f);
            float vs = 0.f;
            for (int q = 0; q < 4; q++) { float d = xs[q]-mu; vs += d*d; }
            for (int m = 32; m >= 1; m >>= 1) vs += __shfl_xor(vs,m,64);
            float rinv = rsqrtf(vs*(1.0f/256.0f)+1e-5f);
            for (int q = 0; q < 4; q++) {
                int k = lane + 64*q;
                sln[k*20 + tt] = (xs[q]-mu)*rinv*ln_g[k] + ln_b[k];
            }
            if (lane == 0) ws[OFF_GATE + tok0 + tt] = 1.0f/(1.0f+expf(-(gdot + bgate[0])));
        }
    }
    __syncthreads();

    if (t < 272) {
        int i = t / 68, j = t - i*68;
        const float* Wc = ws + OFF_WCAT + 4*j;
        float4 acc[4];
        acc[0] = acc[1] = acc[2] = acc[3] = make_float4(0.f,0.f,0.f,0.f);
        #pragma unroll 4
        for (int k = 0; k < 256; k++) {
            float4 a4 = *(const float4*)&sln[k*20 + 4*i];
            float4 w4 = *(const float4*)&Wc[(size_t)k*272];
            fma4x4(a4, w4, acc);
        }
        float4 b4 = *(const float4*)&ws[OFF_BCAT + 4*j];
        for (int ti = 0; ti < 4; ti++) {
            int n = tok0 + 4*i + ti;
            float4 v = acc[ti];
            v.x += b4.x; v.y += b4.y; v.z += b4.z; v.w += b4.w;
            if (j >= 4) {
                *(float4*)&ws[OFF_VW + (size_t)n*256 + (4*j - 16)] = v;
            } else {
                float vv[4] = {v.x, v.y, v.z, v.w};
                for (int c = 0; c < 4; c++) {
                    int col = 4*j + c;
                    if (col < 8) ws[OFF_QA + n*8 + col] = vv[c];
                    else         ws[OFF_KA + n*8 + (col-8)] = vv[c];
                }
            }
        }
    }
}

// ---------------- Kernel 3: per-graph geometry (center, cov, eigh, proj) ----
__global__ __launch_bounds__(256) void k_geo(const float* __restrict__ geo, float* __restrict__ ws)
{
    __shared__ float sred[4 * 9];
    __shared__ float sres[9];
    __shared__ float sV[9];
    int t = threadIdx.x, g = blockIdx.x;
    int wave = t >> 6, lane = t & 63;
    const float* gp = geo + (size_t)g * NPG * 3;

    float x0[2], y0[2], z0[2];
    float sx = 0.f, sy = 0.f, sz = 0.f;
    for (int i = 0; i < 2; i++) {
        int p = t + 256 * i;
        x0[i] = gp[p*3 + 0]; y0[i] = gp[p*3 + 1]; z0[i] = gp[p*3 + 2];
        sx += x0[i]; sy += y0[i]; sz += z0[i];
    }
    {
        float vals[3] = {sx, sy, sz};
        for (int q = 0; q < 3; q++) {
            float v = vals[q];
            for (int m = 32; m >= 1; m >>= 1) v += __shfl_xor(v, m, 64);
            if (lane == 0) sred[wave*9 + q] = v;
        }
    }
    __syncthreads();
    if (t < 3) {
        float s = 0.f;
        for (int w = 0; w < 4; w++) s += sred[w*9 + t];
        sres[t] = s * (1.0f / 512.0f);
    }
    __syncthreads();
    float cx = sres[0], cy = sres[1], cz = sres[2];

    float c6[6] = {0.f, 0.f, 0.f, 0.f, 0.f, 0.f};
    for (int i = 0; i < 2; i++) {
        float dx = x0[i] - cx, dy = y0[i] - cy, dz = z0[i] - cz;
        c6[0] += dx*dx; c6[1] += dx*dy; c6[2] += dx*dz;
        c6[3] += dy*dy; c6[4] += dy*dz; c6[5] += dz*dz;
    }
    for (int q = 0; q < 6; q++) {
        float v = c6[q];
        for (int m = 32; m >= 1; m >>= 1) v += __shfl_xor(v, m, 64);
        if (lane == 0) sred[wave*9 + q] = v;
    }
    __syncthreads();
    if (t < 6) {
        float s = 0.f;
        for (int w = 0; w < 4; w++) s += sred[w*9 + t];
        sres[t] = s;
    }
    __syncthreads();

    if (t == 0) {
        double a[3][3];
        a[0][0] = sres[0]; a[0][1] = a[1][0] = sres[1]; a[0][2] = a[2][0] = sres[2];
        a[1][1] = sres[3]; a[1][2] = a[2][1] = sres[4]; a[2][2] = sres[5];
        double v[3][3] = {{1,0,0},{0,1,0},{0,0,1}};
        const int ps[3] = {0, 0, 1}, qs[3] = {1, 2, 2};
        for (int sweep = 0; sweep < 10; sweep++) {
            for (int pi = 0; pi < 3; pi++) {
                int p = ps[pi], q = qs[pi];
                double apq = a[p][q];
                if (fabs(apq) < 1e-300) continue;
                double theta = (a[q][q] - a[p][p]) / (2.0 * apq);
                double tt = ((theta >= 0.0) ? 1.0 : -1.0) / (fabs(theta) + sqrt(theta*theta + 1.0));
                double c = 1.0 / sqrt(tt*tt + 1.0), s = tt * c;
                int k = 3 - p - q;
                double app = a[p][p], aqq = a[q][q], akp = a[k][p], akq = a[k][q];
                a[p][p] = app - tt * apq;
                a[q][q] = aqq + tt * apq;
                a[p][q] = 0.0; a[q][p] = 0.0;
                a[k][p] = c*akp - s*akq; a[p][k] = a[k][p];
                a[k][q] = s*akp + c*akq; a[q][k] = a[k][q];
                for (int kk = 0; kk < 3; kk++) {
                    double vp = v[kk][p], vq = v[kk][q];
                    v[kk][p] = c*vp - s*vq;
                    v[kk][q] = s*vp + c*vq;
                }
            }
        }
        for (int r = 0; r < 3; r++)
            for (int c2 = 0; c2 < 3; c2++) {
                float fv = (float)v[r][c2];
                sV[r*3 + c2] = fv;
                ws[OFF_VMAT + g*9 + r*3 + c2] = fv;
            }
        ws[OFF_CEN + g*3 + 0] = cx;
        ws[OFF_CEN + g*3 + 1] = cy;
        ws[OFF_CEN + g*3 + 2] = cz;
    }
    __syncthreads();

    for (int i = 0; i < 2; i++) {
        int p = t + 256 * i;
        float dx = x0[i] - cx, dy = y0[i] - cy, dz = z0[i] - cz;
        for (int c = 0; c < 3; c++) {
            float pr = dx * sV[0*3 + c] + dy * sV[1*3 + c] + dz * sV[2*3 + c];
            ws[OFF_PROJ + (size_t)(g*NPG + p)*3 + c] = pr;
        }
    }
}

// ---------------- Kernel 4: fused per-token attention (LDS-pipe-light) -----
// Thread (m=t>>3, sub=t&7) owns 16 edge floats in registers end-to-end:
// global load -> LN (shfl/8) -> all-head logit partials (weights via global,
// L2-hot, wave-dedup) -> butterfly/8 -> lane sub finalizes head sub.
// LDS: se (normalized rows, for edge-agg), sattn (in-place softmax), sew.
__global__ __launch_bounds__(256) void k_attn(
    const float* __restrict__ edge, const int* __restrict__ nbr,
    const void* __restrict__ maskp,
    const float* __restrict__ lneg, const float* __restrict__ lneb,
    const float* __restrict__ bqkve, const float* __restrict__ Wqkve,
    const float* __restrict__ Wfa, const float* __restrict__ bfa,
    const float* __restrict__ geo, float* __restrict__ ws, float* __restrict__ out)
{
    __shared__ __align__(16) float se[32 * 132];     // normalized edge rows
    __shared__ __align__(16) float sew[8 * 132];     // attn-weighted rows
    __shared__ __align__(16) float sattn[8 * 36];    // logits -> attn (in place)
    __shared__ float sbuf[128];                      // edge-ctx K-split partials
    __shared__ int   snbr[32];
    __shared__ int   smask[32];
    __shared__ float sqa[8], sbef[8];
    __shared__ float sg3[4];

    int t = threadIdx.x;
    int n = blockIdx.x;
    int g = n >> 9;
    int flag = ((const int*)(ws + OFF_FLAG))[0];

    // ---- tiny stage (pre-bar1) ----
    if (t < 32) {
        snbr[t] = nbr[n*32 + t];
        int mv;
        if (flag == 1)      mv = (int)((const unsigned char*)maskp)[n*32 + t];
        else if (flag == 2) mv = (((const float*)maskp)[n*32 + t] != 0.0f) ? 1 : 0;
        else                mv = ((const int*)maskp)[n*32 + t];
        smask[t] = mv;
    }
    if (t < 8) { sqa[t] = ws[OFF_QA + n*8 + t]; sbef[t] = ws[OFF_BEF + t]; }

    // ---- phase B: load + LN + logit partials, all in registers ----
    int m = t >> 3, sub = t & 7;
    float4 x0, x1, x2, x3;
    {
        const float4* ep = (const float4*)(edge + (size_t)n*4096 + m*128 + sub*16);
        x0 = ep[0]; x1 = ep[1]; x2 = ep[2]; x3 = ep[3];
    }
    {
        float s = x0.x+x0.y+x0.z+x0.w + x1.x+x1.y+x1.z+x1.w
                + x2.x+x2.y+x2.z+x2.w + x3.x+x3.y+x3.z+x3.w;
        for (int mm = 4; mm >= 1; mm >>= 1) s += __shfl_xor(s, mm, 8);
        float mu = s * (1.0f / 128.0f);
        float vs = (x0.x-mu)*(x0.x-mu) + (x0.y-mu)*(x0.y-mu) + (x0.z-mu)*(x0.z-mu) + (x0.w-mu)*(x0.w-mu)
                 + (x1.x-mu)*(x1.x-mu) + (x1.y-mu)*(x1.y-mu) + (x1.z-mu)*(x1.z-mu) + (x1.w-mu)*(x1.w-mu)
                 + (x2.x-mu)*(x2.x-mu) + (x2.y-mu)*(x2.y-mu) + (x2.z-mu)*(x2.z-mu) + (x2.w-mu)*(x2.w-mu)
                 + (x3.x-mu)*(x3.x-mu) + (x3.y-mu)*(x3.y-mu) + (x3.z-mu)*(x3.z-mu) + (x3.w-mu)*(x3.w-mu);
        for (int mm = 4; mm >= 1; mm >>= 1) vs += __shfl_xor(vs, mm, 8);
        float rinv = rsqrtf(vs * (1.0f / 128.0f) + 1e-5f);
        const float4* gp4 = (const float4*)(lneg + sub*16);
        const float4* bp4 = (const float4*)(lneb + sub*16);
        float4 g0 = gp4[0], g1 = gp4[1], g2 = gp4[2], g3 = gp4[3];
        float4 b0 = bp4[0], b1 = bp4[1], b2 = bp4[2], b3 = bp4[3];
        x0.x=(x0.x-mu)*rinv*g0.x+b0.x; x0.y=(x0.y-mu)*rinv*g0.y+b0.y;
        x0.z=(x0.z-mu)*rinv*g0.z+b0.z; x0.w=(x0.w-mu)*rinv*g0.w+b0.w;
        x1.x=(x1.x-mu)*rinv*g1.x+b1.x; x1.y=(x1.y-mu)*rinv*g1.y+b1.y;
        x1.z=(x1.z-mu)*rinv*g1.z+b1.z; x1.w=(x1.w-mu)*rinv*g1.w+b1.w;
        x2.x=(x2.x-mu)*rinv*g2.x+b2.x; x2.y=(x2.y-mu)*rinv*g2.y+b2.y;
        x2.z=(x2.z-mu)*rinv*g2.z+b2.z; x2.w=(x2.w-mu)*rinv*g2.w+b2.w;
        x3.x=(x3.x-mu)*rinv*g3.x+b3.x; x3.y=(x3.y-mu)*rinv*g3.y+b3.y;
        x3.z=(x3.z-mu)*rinv*g3.z+b3.z; x3.w=(x3.w-mu)*rinv*g3.w+b3.w;
    }
    {
        int base = m*132 + sub*16;
        *(float4*)&se[base + 0]  = x0;
        *(float4*)&se[base + 4]  = x1;
        *(float4*)&se[base + 8]  = x2;
        *(float4*)&se[base + 12] = x3;
    }
    float acc[8];
    {
        const float* wef = ws + OFF_WEF + sub*16;
        #pragma unroll
        for (int h = 0; h < 8; h++) {
            const float4* wp = (const float4*)(wef + h*128);
            float4 w0 = wp[0], w1 = wp[1], w2 = wp[2], w3 = wp[3];
            acc[h] = dot4(x0,w0) + dot4(x1,w1) + dot4(x2,w2) + dot4(x3,w3);
        }
        #pragma unroll
        for (int st = 1; st < 8; st <<= 1) {
            #pragma unroll
            for (int h = 0; h < 8; h++) acc[h] += __shfl_xor(acc[h], st, 8);
        }
    }
    __syncthreads();   // bar1: stage + se writes visible

    // ---- finalize logit for head (sub) of row m ----
    {
        float myacc = acc[0];
        #pragma unroll
        for (int h = 1; h < 8; h++) myacc = (sub == h) ? acc[h] : myacc;
        float lg = sqa[sub] + sbef[sub] + myacc + ws[OFF_KA + snbr[m]*8 + sub];
        if (!smask[m]) lg = -1e9f;
        sattn[sub*36 + m] = lg;
    }
    __syncthreads();   // bar2

    // ---- softmax over m per h (in place) ----
    {
        int h = t >> 5, mm2 = t & 31;
        float x = sattn[h*36 + mm2];
        float mx = x;
        for (int mm = 16; mm >= 1; mm >>= 1) mx = fmaxf(mx, __shfl_xor(mx, mm, 32));
        float e = expf(x - mx);
        float sum = e;
        for (int mm = 16; mm >= 1; mm >>= 1) sum += __shfl_xor(sum, mm, 32);
        sattn[h*36 + mm2] = e / sum;
    }
    __syncthreads();   // bar3

    // ---- phase C: scalar ctx + edge agg (attn in registers) + wm/geo -------
    {
        int h = t >> 5;
        float av[32];
        #pragma unroll
        for (int k = 0; k < 8; k++) *(float4*)&av[4*k] = *(const float4*)&sattn[h*36 + 4*k];

        // scalar context: column t of hcat
        float accS = 0.f;
        const float* vw = ws + OFF_VW;
        #pragma unroll
        for (int mm2 = 0; mm2 < 32; mm2++) {
            int row = snbr[mm2];
            accS += av[mm2] * vw[(size_t)row*256 + t];
        }
        ws[OFF_HCAT + (size_t)n*384 + t] = accS;

        // edge agg
        int rq = t & 31;
        float4 eacc = make_float4(0.f,0.f,0.f,0.f);
        #pragma unroll
        for (int mm2 = 0; mm2 < 32; mm2++) {
            float a = av[mm2];
            float4 e4 = *(const float4*)&se[mm2*132 + rq*4];
            eacc.x += a*e4.x; eacc.y += a*e4.y; eacc.z += a*e4.z; eacc.w += a*e4.w;
        }
        *(float4*)&sew[h*132 + rq*4] = eacc;
    }
    if (t < 32) {
        // wm in-register + geo products + shfl reduce (wave 0 low half)
        float wmv = 0.f;
        #pragma unroll
        for (int h2 = 0; h2 < 8; h2++) wmv += Wfa[h2] * sattn[h2*36 + t];
        int row = snbr[t];
        const float* pp = ws + OFF_PROJ + (size_t)row*3;
        float q0 = wmv * pp[0], q1 = wmv * pp[1], q2 = wmv * pp[2];
        for (int st = 16; st >= 1; st >>= 1) {
            q0 += __shfl_xor(q0, st, 32);
            q1 += __shfl_xor(q1, st, 32);
            q2 += __shfl_xor(q2, st, 32);
        }
        if (t < 3) {
            float sd = (t == 0) ? q0 : (t == 1) ? q1 : q2;
            float bb = bfa[0];
            float p1 = sd + bb, p2 = -sd + bb;
            float s1v = p1 / (1.0f + expf(-p1));
            float s2v = p2 / (1.0f + expf(-p2));
            sg3[t] = 0.5f * (s1v - s2v);
        }
    }
    __syncthreads();   // bar4

    // ---- phase D: edge ctx (K-split over 256 threads) ----
    float accEC;
    {
        int col = t & 127, half = t >> 7;
        int h2 = col >> 4;
        int rbase = half * 64;
        const float* wq = Wqkve + 128 + col;
        float a0 = 0.f;
        #pragma unroll
        for (int k = 0; k < 16; k++) {
            int r = rbase + 4*k;
            float4 s4 = *(const float4*)&sew[h2*132 + r];
            a0 += s4.x * wq[(size_t)(r+0)*256]
                + s4.y * wq[(size_t)(r+1)*256]
                + s4.z * wq[(size_t)(r+2)*256]
                + s4.w * wq[(size_t)(r+3)*256];
        }
        accEC = a0;
        if (half) sbuf[col] = a0;
    }
    __syncthreads();   // bar5

    if (t < 128) {
        ws[OFF_HCAT + (size_t)n*384 + 256 + t] = accEC + sbuf[t] + bqkve[128 + t];
    }
    if (t < 3) {
        const float* Vm = ws + OFF_VMAT + g*9;
        float gc = Vm[t*3+0]*sg3[0] + Vm[t*3+1]*sg3[1] + Vm[t*3+2]*sg3[2] + ws[OFF_CEN + g*3 + t];
        float gt = ws[OFF_GATE + n];
        out[OUT_GEO_OFF + (size_t)n*3 + t] = gc * gt + geo[(size_t)n*3 + t] * (1.0f - gt);
    }
}

// ---------------- Kernel 5: MLP — register-tiled fc1+gelu+LN+fc2+residual --
__global__ __launch_bounds__(256) void k_mlp(
    const float* __restrict__ tok, const float* __restrict__ Wfc1,
    const float* __restrict__ bfc1, const float* __restrict__ lnhg,
    const float* __restrict__ lnhb, const float* __restrict__ Wfc2,
    const float* __restrict__ bfc2, const float* __restrict__ ws,
    float* __restrict__ out)
{
    __shared__ __align__(16) float A[384 * 20];
    int t = threadIdx.x;
    int tok0 = blockIdx.x * 16;
    int i = t >> 6, j = t & 63;
    const float* hc = ws + OFF_HCAT;

    for (int it = 0; it < 24; it++) {
        int idx = it*256 + t;
        int tt = idx / 384;
        int k  = idx - tt*384;
        A[k*20 + tt] = hc[(size_t)tok0*384 + idx];
    }
    __syncthreads();

    float4 acc1[4];
    acc1[0] = acc1[1] = acc1[2] = acc1[3] = make_float4(0.f,0.f,0.f,0.f);
    {
        const float* wp = Wfc1 + 4*j;
        #pragma unroll 4
        for (int k = 0; k < 384; k++) {
            float4 a4 = *(const float4*)&A[k*20 + 4*i];
            float4 w4 = *(const float4*)&wp[(size_t)k*256];
            fma4x4(a4, w4, acc1);
        }
    }
    float h[4][4];
    {
        float4 b4 = *(const float4*)&bfc1[4*j];
        for (int ti = 0; ti < 4; ti++) {
            float xv[4] = {acc1[ti].x + b4.x, acc1[ti].y + b4.y, acc1[ti].z + b4.z, acc1[ti].w + b4.w};
            for (int c = 0; c < 4; c++) {
                float x = xv[c];
                h[ti][c] = 0.5f * x * (1.0f + erff(x * 0.70710678118654752f));
            }
        }
    }
    __syncthreads();

    {
        float s[4], q[4];
        for (int ti = 0; ti < 4; ti++) {
            s[ti] = h[ti][0] + h[ti][1] + h[ti][2] + h[ti][3];
            q[ti] = h[ti][0]*h[ti][0] + h[ti][1]*h[ti][1] + h[ti][2]*h[ti][2] + h[ti][3]*h[ti][3];
        }
        for (int m = 32; m >= 1; m >>= 1)
            for (int ti = 0; ti < 4; ti++) {
                s[ti] += __shfl_xor(s[ti], m, 64);
                q[ti] += __shfl_xor(q[ti], m, 64);
            }
        float4 g4 = *(const float4*)&lnhg[4*j];
        float4 b4 = *(const float4*)&lnhb[4*j];
        float gg[4] = {g4.x, g4.y, g4.z, g4.w};
        float bb[4] = {b4.x, b4.y, b4.z, b4.w};
        for (int ti = 0; ti < 4; ti++) {
            float mu = s[ti] * (1.0f/256.0f);
            float var = q[ti] * (1.0f/256.0f) - mu*mu;
            float rinv = rsqrtf(var + 1e-5f);
            for (int c = 0; c < 4; c++) {
                float hn = (h[ti][c] - mu) * rinv * gg[c] + bb[c];
                A[(4*j + c)*20 + 4*i + ti] = hn;
            }
        }
    }
    __syncthreads();

    float4 acc2[4];
    acc2[0] = acc2[1] = acc2[2] = acc2[3] = make_float4(0.f,0.f,0.f,0.f);
    {
        const float* wp = Wfc2 + 4*j;
        #pragma unroll 4
        for (int k = 0; k < 256; k++) {
            float4 a4 = *(const float4*)&A[k*20 + 4*i];
            float4 w4 = *(const float4*)&wp[(size_t)k*256];
            fma4x4(a4, w4, acc2);
        }
    }
    {
        float4 b4 = *(const float4*)&bfc2[4*j];
        for (int ti = 0; ti < 4; ti++) {
            size_t o = (size_t)(tok0 + 4*i + ti) * 256 + 4*j;
            float4 r4 = *(const float4*)&tok[o];
            float4 v;
            v.x = acc2[ti].x + b4.x + r4.x;
            v.y = acc2[ti].y + b4.y + r4.y;
            v.z = acc2[ti].z + b4.z + r4.z;
            v.w = acc2[ti].w + b4.w + r4.w;
            *(float4*)&out[o] = v;
        }
    }
}

extern "C" void kernel_launch(void* const* d_in, const int* in_sizes, int n_in,
                              void* d_out, int out_size, void* d_ws, size_t ws_size,
                              hipStream_t stream) {
    (void)in_sizes; (void)n_in; (void)out_size; (void)ws_size;
    const float* tok   = (const float*)d_in[0];
    const float* geo   = (const float*)d_in[1];
    const float* edge  = (const float*)d_in[2];
    const int*   nbr   = (const int*)d_in[3];
    const void*  maskp = d_in[5];
    const float* ln_qkv_g = (const float*)d_in[6];
    const float* ln_qkv_b = (const float*)d_in[7];
    const float* Wqkv  = (const float*)d_in[8];
    const float* bqkv  = (const float*)d_in[9];
    const float* ln_e_g = (const float*)d_in[10];
    const float* ln_e_b = (const float*)d_in[11];
    const float* Wqkve = (const float*)d_in[12];
    const float* bqkve = (const float*)d_in[13];
    const float* w_attn = (const float*)d_in[14];
    const float* w_edge = (const float*)d_in[15];
    const float* Wgate = (const float*)d_in[16];
    const float* bgate = (const float*)d_in[17];
    const float* Wfc1  = (const float*)d_in[18];
    const float* bfc1  = (const float*)d_in[19];
    const float* lnhg  = (const float*)d_in[20];
    const float* lnhb  = (const float*)d_in[21];
    const float* Wfc2  = (const float*)d_in[22];
    const float* bfc2  = (const float*)d_in[23];
    const float* Wfa   = (const float*)d_in[24];
    const float* bfa   = (const float*)d_in[25];
    float* ws  = (float*)d_ws;
    float* out = (float*)d_out;

    k_fold<<<dim3(279), dim3(256), 0, stream>>>(Wqkv, bqkv, Wqkve, bqkve, w_attn, w_edge,
                                                (const int*)maskp, ws);
    k_tokprep<<<dim3(512), dim3(320), 0, stream>>>(tok, ln_qkv_g, ln_qkv_b, Wgate, bgate, ws);
    k_geo<<<dim3(16), dim3(256), 0, stream>>>(geo, ws);
    k_attn<<<dim3(8192), dim3(256), 0, stream>>>(edge, nbr, maskp, ln_e_g, ln_e_b, bqkve,
                                                 Wqkve, Wfa, bfa, geo, ws, out);
    k_mlp<<<dim3(512), dim3(256), 0, stream>>>(tok, Wfc1, bfc1, lnhg, lnhb, Wfc2, bfc2, ws, out);
}

// Round 4
// 437.709 us; speedup vs baseline: 1.0709x; 1.0709x over previous
//
#include <hip/hip_runtime.h>
#include <math.h>

#define NTOK 8192
#define NPG  512
#define MNEI 32
#define DM   256
#define DE   128
#define NH   8

// workspace offsets (in floats)
#define OFF_WCAT  0u          // 256*272   [k][272] : cols 0..7 qa, 8..15 ka, 16..271 v
#define OFF_BCAT  69632u      // 272
#define OFF_WEF   69904u      // 8*128  [h][r]
#define OFF_BEF   70928u      // 8
#define OFF_FLAG  70936u      // 1 int (pad to 70944)
#define OFF_QA    70944u      // 8192*8
#define OFF_KA    136480u     // 8192*8
#define OFF_GATE  202016u     // 8192
#define OFF_VW    210208u     // 8192*256
#define OFF_PROJ  2307360u    // 8192*3
#define OFF_VMAT  2331936u    // 16*9
#define OFF_CEN   2332080u    // 16*3
#define OFF_HCAT  2332128u    // 8192*384

#define OUT_GEO_OFF 2097152   // 8192*256

__device__ __forceinline__ void fma4x4(const float4 a, const float4 w, float4* acc) {
    acc[0].x += a.x*w.x; acc[0].y += a.x*w.y; acc[0].z += a.x*w.z; acc[0].w += a.x*w.w;
    acc[1].x += a.y*w.x; acc[1].y += a.y*w.y; acc[1].z += a.y*w.z; acc[1].w += a.y*w.w;
    acc[2].x += a.z*w.x; acc[2].y += a.z*w.y; acc[2].z += a.z*w.z; acc[2].w += a.z*w.w;
    acc[3].x += a.w*w.x; acc[3].y += a.w*w.y; acc[3].z += a.w*w.z; acc[3].w += a.w*w.w;
}

// ---------------- Kernel 1: weight folding + mask layout detection ----------
__global__ __launch_bounds__(256) void k_fold(
    const float* __restrict__ Wqkv, const float* __restrict__ bqkv,
    const float* __restrict__ Wqkve, const float* __restrict__ bqkve,
    const float* __restrict__ w_attn, const float* __restrict__ w_edge,
    const int* __restrict__ maskp, float* __restrict__ ws)
{
    int t = threadIdx.x;
    if (blockIdx.x == 0) {
        __shared__ int sbad, sflt;
        if (t == 0) { sbad = 0; sflt = 0; }
        __syncthreads();
        int bad = 0, flt = 0;
        for (int i = 0; i < 256; i++) {
            unsigned int w = (unsigned int)maskp[i*256 + t];
            if (w > 1u) bad = 1;
            if (w == 0x3F800000u) flt = 1;
        }
        if (bad) atomicOr(&sbad, 1);
        if (flt) atomicOr(&sflt, 1);
        __syncthreads();
        if (t == 0) {
            int f = sflt ? 2 : (sbad ? 1 : 0);
            ((int*)(ws + OFF_FLAG))[0] = f;
        }
        return;
    }
    int gid = (blockIdx.x - 1) * 256 + t;
    if (gid < 69632) {
        int r = gid / 272, c = gid % 272;
        float val;
        if (c < 16) {
            int h = c & 7; int off = (c < 8) ? 0 : 256;
            float s = 0.f;
            for (int d = 0; d < 32; d++) s += Wqkv[r*768 + off + h*32 + d] * w_attn[d];
            val = s;
        } else {
            val = Wqkv[r*768 + 512 + (c - 16)];
        }
        ws[OFF_WCAT + gid] = val;
    } else if (gid < 69632 + 272) {
        int c = gid - 69632;
        float val;
        if (c < 16) {
            int h = c & 7; int off = (c < 8) ? 0 : 256;
            float s = 0.f;
            for (int d = 0; d < 32; d++) s += bqkv[off + h*32 + d] * w_attn[d];
            val = s;
        } else {
            val = bqkv[512 + (c - 16)];
        }
        ws[OFF_BCAT + c] = val;
    } else if (gid < 69904 + 1024) {
        int i = gid - 69904;
        int h = i >> 7, r = i & 127;
        float s = 0.f;
        for (int e = 0; e < 16; e++) s += Wqkve[r*256 + h*16 + e] * w_edge[e];
        ws[OFF_WEF + i] = s;
    } else if (gid < 70928 + 8) {
        int h = gid - 70928;
        float s = 0.f;
        for (int e = 0; e < 16; e++) s += bqkve[h*16 + e] * w_edge[e];
        ws[OFF_BEF + h] = s;
    }
}

// ---------------- Kernel 2: token LN + gate + [qa|ka|v] register-tiled GEMM
__global__ __launch_bounds__(320) void k_tokprep(
    const float* __restrict__ tok, const float* __restrict__ ln_g,
    const float* __restrict__ ln_b, const float* __restrict__ Wgate,
    const float* __restrict__ bgate, float* __restrict__ ws)
{
    __shared__ __align__(16) float sln[256 * 20];
    int t = threadIdx.x;
    int tok0 = blockIdx.x * 16;

    for (int idx = t; idx < 4096; idx += 320) {
        int tt = idx >> 8, k = idx & 255;
        sln[k*20 + tt] = tok[(size_t)(tok0 + tt) * 256 + k];
    }
    __syncthreads();

    int wave = t >> 6, lane = t & 63;
    if (wave < 4) {
        for (int rr = 0; rr < 4; rr++) {
            int tt = wave * 4 + rr;
            float s = 0.f, gdot = 0.f;
            float xs[4];
            for (int q = 0; q < 4; q++) {
                int k = lane + 64*q;
                float x = sln[k*20 + tt];
                xs[q] = x; s += x; gdot += x * Wgate[k];
            }
            for (int m = 32; m >= 1; m >>= 1) { s += __shfl_xor(s,m,64); gdot += __shfl_xor(gdot,m,64); }
            float mu = s * (1.0f/256.0f);
            float vs = 0.f;
            for (int q = 0; q < 4; q++) { float d = xs[q]-mu; vs += d*d; }
            for (int m = 32; m >= 1; m >>= 1) vs += __shfl_xor(vs,m,64);
            float rinv = rsqrtf(vs*(1.0f/256.0f)+1e-5f);
            for (int q = 0; q < 4; q++) {
                int k = lane + 64*q;
                sln[k*20 + tt] = (xs[q]-mu)*rinv*ln_g[k] + ln_b[k];
            }
            if (lane == 0) ws[OFF_GATE + tok0 + tt] = 1.0f/(1.0f+expf(-(gdot + bgate[0])));
        }
    }
    __syncthreads();

    if (t < 272) {
        int i = t / 68, j = t - i*68;
        const float* Wc = ws + OFF_WCAT + 4*j;
        float4 acc[4];
        acc[0] = acc[1] = acc[2] = acc[3] = make_float4(0.f,0.f,0.f,0.f);
        #pragma unroll 4
        for (int k = 0; k < 256; k++) {
            float4 a4 = *(const float4*)&sln[k*20 + 4*i];
            float4 w4 = *(const float4*)&Wc[(size_t)k*272];
            fma4x4(a4, w4, acc);
        }
        float4 b4 = *(const float4*)&ws[OFF_BCAT + 4*j];
        for (int ti = 0; ti < 4; ti++) {
            int n = tok0 + 4*i + ti;
            float4 v = acc[ti];
            v.x += b4.x; v.y += b4.y; v.z += b4.z; v.w += b4.w;
            if (j >= 4) {
                *(float4*)&ws[OFF_VW + (size_t)n*256 + (4*j - 16)] = v;
            } else {
                float vv[4] = {v.x, v.y, v.z, v.w};
                for (int c = 0; c < 4; c++) {
                    int col = 4*j + c;
                    if (col < 8) ws[OFF_QA + n*8 + col] = vv[c];
                    else         ws[OFF_KA + n*8 + (col-8)] = vv[c];
                }
            }
        }
    }
}

// ---------------- Kernel 3: per-graph geometry (center, cov, eigh, proj) ----
__global__ __launch_bounds__(256) void k_geo(const float* __restrict__ geo, float* __restrict__ ws)
{
    __shared__ float sred[4 * 9];
    __shared__ float sres[9];
    __shared__ float sV[9];
    int t = threadIdx.x, g = blockIdx.x;
    int wave = t >> 6, lane = t & 63;
    const float* gp = geo + (size_t)g * NPG * 3;

    float x0[2], y0[2], z0[2];
    float sx = 0.f, sy = 0.f, sz = 0.f;
    for (int i = 0; i < 2; i++) {
        int p = t + 256 * i;
        x0[i] = gp[p*3 + 0]; y0[i] = gp[p*3 + 1]; z0[i] = gp[p*3 + 2];
        sx += x0[i]; sy += y0[i]; sz += z0[i];
    }
    {
        float vals[3] = {sx, sy, sz};
        for (int q = 0; q < 3; q++) {
            float v = vals[q];
            for (int m = 32; m >= 1; m >>= 1) v += __shfl_xor(v, m, 64);
            if (lane == 0) sred[wave*9 + q] = v;
        }
    }
    __syncthreads();
    if (t < 3) {
        float s = 0.f;
        for (int w = 0; w < 4; w++) s += sred[w*9 + t];
        sres[t] = s * (1.0f / 512.0f);
    }
    __syncthreads();
    float cx = sres[0], cy = sres[1], cz = sres[2];

    float c6[6] = {0.f, 0.f, 0.f, 0.f, 0.f, 0.f};
    for (int i = 0; i < 2; i++) {
        float dx = x0[i] - cx, dy = y0[i] - cy, dz = z0[i] - cz;
        c6[0] += dx*dx; c6[1] += dx*dy; c6[2] += dx*dz;
        c6[3] += dy*dy; c6[4] += dy*dz; c6[5] += dz*dz;
    }
    for (int q = 0; q < 6; q++) {
        float v = c6[q];
        for (int m = 32; m >= 1; m >>= 1) v += __shfl_xor(v, m, 64);
        if (lane == 0) sred[wave*9 + q] = v;
    }
    __syncthreads();
    if (t < 6) {
        float s = 0.f;
        for (int w = 0; w < 4; w++) s += sred[w*9 + t];
        sres[t] = s;
    }
    __syncthreads();

    if (t == 0) {
        double a[3][3];
        a[0][0] = sres[0]; a[0][1] = a[1][0] = sres[1]; a[0][2] = a[2][0] = sres[2];
        a[1][1] = sres[3]; a[1][2] = a[2][1] = sres[4]; a[2][2] = sres[5];
        double v[3][3] = {{1,0,0},{0,1,0},{0,0,1}};
        const int ps[3] = {0, 0, 1}, qs[3] = {1, 2, 2};
        for (int sweep = 0; sweep < 10; sweep++) {
            for (int pi = 0; pi < 3; pi++) {
                int p = ps[pi], q = qs[pi];
                double apq = a[p][q];
                if (fabs(apq) < 1e-300) continue;
                double theta = (a[q][q] - a[p][p]) / (2.0 * apq);
                double tt = ((theta >= 0.0) ? 1.0 : -1.0) / (fabs(theta) + sqrt(theta*theta + 1.0));
                double c = 1.0 / sqrt(tt*tt + 1.0), s = tt * c;
                int k = 3 - p - q;
                double app = a[p][p], aqq = a[q][q], akp = a[k][p], akq = a[k][q];
                a[p][p] = app - tt * apq;
                a[q][q] = aqq + tt * apq;
                a[p][q] = 0.0; a[q][p] = 0.0;
                a[k][p] = c*akp - s*akq; a[p][k] = a[k][p];
                a[k][q] = s*akp + c*akq; a[q][k] = a[k][q];
                for (int kk = 0; kk < 3; kk++) {
                    double vp = v[kk][p], vq = v[kk][q];
                    v[kk][p] = c*vp - s*vq;
                    v[kk][q] = s*vp + c*vq;
                }
            }
        }
        for (int r = 0; r < 3; r++)
            for (int c2 = 0; c2 < 3; c2++) {
                float fv = (float)v[r][c2];
                sV[r*3 + c2] = fv;
                ws[OFF_VMAT + g*9 + r*3 + c2] = fv;
            }
        ws[OFF_CEN + g*3 + 0] = cx;
        ws[OFF_CEN + g*3 + 1] = cy;
        ws[OFF_CEN + g*3 + 2] = cz;
    }
    __syncthreads();

    for (int i = 0; i < 2; i++) {
        int p = t + 256 * i;
        float dx = x0[i] - cx, dy = y0[i] - cy, dz = z0[i] - cz;
        for (int c = 0; c < 3; c++) {
            float pr = dx * sV[0*3 + c] + dy * sV[1*3 + c] + dz * sV[2*3 + c];
            ws[OFF_PROJ + (size_t)(g*NPG + p)*3 + c] = pr;
        }
    }
}

// ---------------- Kernel 4: fused per-token attention ----------------------
// Round-2 skeleton (LDS stage + LN + LDS logits) with wave-specialized
// phase C (waves 0-1: float4 scalar-ctx gathers; waves 2-3: edge agg at
// 2 heads/thread) and coalesced-float4 edge-ctx with K-split reduce through
// sec (aliases dead se).
__global__ __launch_bounds__(256) void k_attn(
    const float* __restrict__ edge, const int* __restrict__ nbr,
    const void* __restrict__ maskp,
    const float* __restrict__ lneg, const float* __restrict__ lneb,
    const float* __restrict__ bqkve, const float* __restrict__ Wqkve,
    const float* __restrict__ Wfa, const float* __restrict__ bfa,
    const float* __restrict__ geo, float* __restrict__ ws, float* __restrict__ out)
{
    __shared__ __align__(16) float se[32 * 132];    // LN rows; sec aliases after bar4
    __shared__ __align__(16) float swe[8 * 132];    // logit weights
    __shared__ __align__(16) float sew[8 * 132];    // attn-weighted rows
    __shared__ __align__(16) float sattn[8 * 36];   // logits -> attn (in place)
    __shared__ __align__(16) float sq[64 * 4];      // wave-1 scalar-ctx partials
    __shared__ int   snbr[32];
    __shared__ int   smask[32];
    __shared__ float sqa[8], sbef[8];
    __shared__ float sge[128], sbe[128];
    __shared__ float sg3[4];

    int t = threadIdx.x;
    int n = blockIdx.x;
    int g = n >> 9;
    int flag = ((const int*)(ws + OFF_FLAG))[0];

    // ---- phase 1: stage ----
    if (t < 32) {
        snbr[t] = nbr[n*32 + t];
        int mv;
        if (flag == 1)      mv = (int)((const unsigned char*)maskp)[n*32 + t];
        else if (flag == 2) mv = (((const float*)maskp)[n*32 + t] != 0.0f) ? 1 : 0;
        else                mv = ((const int*)maskp)[n*32 + t];
        smask[t] = mv;
    }
    if (t < 8) { sqa[t] = ws[OFF_QA + n*8 + t]; sbef[t] = ws[OFF_BEF + t]; }
    if (t >= 32 && t < 160) { sge[t - 32] = lneg[t - 32]; sbe[t - 32] = lneb[t - 32]; }
    {
        // logit weights: float4 per thread (idx t*4..t*4+3 all within one row)
        int idx = t * 4;
        int h = idx >> 7, r = idx & 127;
        *(float4*)&swe[h*132 + r] = *(const float4*)&ws[OFF_WEF + idx];
    }
    {
        const float4* ep = (const float4*)(edge + (size_t)n * 4096);
        for (int j = 0; j < 4; j++) {
            int l = j*1024 + t*4;
            float4 v4 = ep[l >> 2];
            int m = l >> 7, r = l & 127;
            *(float4*)&se[m*132 + r] = v4;
        }
    }
    __syncthreads();   // bar1

    // ---- phase 2: edge-row layernorm (8 threads per row) ----
    {
        int m = t >> 3, sub = t & 7;
        int base = m*132 + sub*16;
        float4 x0 = *(float4*)&se[base + 0];
        float4 x1 = *(float4*)&se[base + 4];
        float4 x2 = *(float4*)&se[base + 8];
        float4 x3 = *(float4*)&se[base + 12];
        float s = x0.x+x0.y+x0.z+x0.w + x1.x+x1.y+x1.z+x1.w
                + x2.x+x2.y+x2.z+x2.w + x3.x+x3.y+x3.z+x3.w;
        for (int mm = 4; mm >= 1; mm >>= 1) s += __shfl_xor(s, mm, 8);
        float mu = s * (1.0f / 128.0f);
        float vs = (x0.x-mu)*(x0.x-mu) + (x0.y-mu)*(x0.y-mu) + (x0.z-mu)*(x0.z-mu) + (x0.w-mu)*(x0.w-mu)
                 + (x1.x-mu)*(x1.x-mu) + (x1.y-mu)*(x1.y-mu) + (x1.z-mu)*(x1.z-mu) + (x1.w-mu)*(x1.w-mu)
                 + (x2.x-mu)*(x2.x-mu) + (x2.y-mu)*(x2.y-mu) + (x2.z-mu)*(x2.z-mu) + (x2.w-mu)*(x2.w-mu)
                 + (x3.x-mu)*(x3.x-mu) + (x3.y-mu)*(x3.y-mu) + (x3.z-mu)*(x3.z-mu) + (x3.w-mu)*(x3.w-mu);
        for (int mm = 4; mm >= 1; mm >>= 1) vs += __shfl_xor(vs, mm, 8);
        float rinv = rsqrtf(vs * (1.0f / 128.0f) + 1e-5f);
        int r0 = sub * 16;
        x0.x = (x0.x-mu)*rinv*sge[r0+0]  + sbe[r0+0];  x0.y = (x0.y-mu)*rinv*sge[r0+1]  + sbe[r0+1];
        x0.z = (x0.z-mu)*rinv*sge[r0+2]  + sbe[r0+2];  x0.w = (x0.w-mu)*rinv*sge[r0+3]  + sbe[r0+3];
        x1.x = (x1.x-mu)*rinv*sge[r0+4]  + sbe[r0+4];  x1.y = (x1.y-mu)*rinv*sge[r0+5]  + sbe[r0+5];
        x1.z = (x1.z-mu)*rinv*sge[r0+6]  + sbe[r0+6];  x1.w = (x1.w-mu)*rinv*sge[r0+7]  + sbe[r0+7];
        x2.x = (x2.x-mu)*rinv*sge[r0+8]  + sbe[r0+8];  x2.y = (x2.y-mu)*rinv*sge[r0+9]  + sbe[r0+9];
        x2.z = (x2.z-mu)*rinv*sge[r0+10] + sbe[r0+10]; x2.w = (x2.w-mu)*rinv*sge[r0+11] + sbe[r0+11];
        x3.x = (x3.x-mu)*rinv*sge[r0+12] + sbe[r0+12]; x3.y = (x3.y-mu)*rinv*sge[r0+13] + sbe[r0+13];
        x3.z = (x3.z-mu)*rinv*sge[r0+14] + sbe[r0+14]; x3.w = (x3.w-mu)*rinv*sge[r0+15] + sbe[r0+15];
        *(float4*)&se[base + 0]  = x0;
        *(float4*)&se[base + 4]  = x1;
        *(float4*)&se[base + 8]  = x2;
        *(float4*)&se[base + 12] = x3;
    }
    __syncthreads();   // bar2

    // ---- phase 3: logits (broadcast-friendly LDS reads) ----
    {
        int m = t >> 3, h = t & 7;
        float acc = sbef[h];
        #pragma unroll 8
        for (int r = 0; r < 128; r += 4) {
            float4 e4 = *(float4*)&se[m*132 + r];
            float4 w4 = *(float4*)&swe[h*132 + r];
            acc += e4.x*w4.x + e4.y*w4.y + e4.z*w4.z + e4.w*w4.w;
        }
        float lg = sqa[h] + acc + ws[OFF_KA + snbr[m]*8 + h];
        if (!smask[m]) lg = -1e9f;
        sattn[h*36 + m] = lg;
    }
    __syncthreads();   // bar3

    // ---- phase 4: softmax over m per h (in place) ----
    {
        int h = t >> 5, m2 = t & 31;
        float x = sattn[h*36 + m2];
        float mx = x;
        for (int mm = 16; mm >= 1; mm >>= 1) mx = fmaxf(mx, __shfl_xor(mx, mm, 32));
        float e = expf(x - mx);
        float sum = e;
        for (int mm = 16; mm >= 1; mm >>= 1) sum += __shfl_xor(sum, mm, 32);
        sattn[h*36 + m2] = e / sum;
    }
    __syncthreads();   // bar4a

    // ---- phase C: wave-specialized ----
    float4 accS = make_float4(0.f,0.f,0.f,0.f);
    if (t < 128) {
        // scalar ctx: half = t>>6 covers 16 m's; c4 = t&63 covers cols 4c4..4c4+3
        int half = t >> 6, c4 = t & 63;
        int h = c4 >> 3;
        const float* vw = ws + OFF_VW;
        #pragma unroll 4
        for (int mi = 0; mi < 16; mi++) {
            int m = half*16 + mi;
            float a = sattn[h*36 + m];
            int row = snbr[m];
            float4 v4 = *(const float4*)&vw[(size_t)row*256 + 4*c4];
            accS.x += a*v4.x; accS.y += a*v4.y; accS.z += a*v4.z; accS.w += a*v4.w;
        }
        if (half) *(float4*)&sq[c4*4] = accS;
        // wm + geo products (lanes 0..31 of wave 0)
        if (t < 32) {
            float wmv = 0.f;
            #pragma unroll
            for (int h2 = 0; h2 < 8; h2++) wmv += Wfa[h2] * sattn[h2*36 + t];
            int row = snbr[t];
            const float* pp = ws + OFF_PROJ + (size_t)row*3;
            float q0 = wmv * pp[0], q1 = wmv * pp[1], q2 = wmv * pp[2];
            for (int st = 16; st >= 1; st >>= 1) {
                q0 += __shfl_xor(q0, st, 32);
                q1 += __shfl_xor(q1, st, 32);
                q2 += __shfl_xor(q2, st, 32);
            }
            if (t < 3) {
                float sd = (t == 0) ? q0 : (t == 1) ? q1 : q2;
                float bb = bfa[0];
                float p1 = sd + bb, p2 = -sd + bb;
                float s1v = p1 / (1.0f + expf(-p1));
                float s2v = p2 / (1.0f + expf(-p2));
                sg3[t] = 0.5f * (s1v - s2v);
            }
        }
    } else {
        // edge agg: 2 heads per thread (hb, hb+4), rq = t&31
        int rq = t & 31, hb = (t >> 5) - 4;
        float4 e1 = make_float4(0.f,0.f,0.f,0.f);
        float4 e2 = make_float4(0.f,0.f,0.f,0.f);
        #pragma unroll
        for (int mq = 0; mq < 8; mq++) {
            float4 a4a = *(const float4*)&sattn[hb*36 + 4*mq];
            float4 a4b = *(const float4*)&sattn[(hb+4)*36 + 4*mq];
            float aa[4] = {a4a.x, a4a.y, a4a.z, a4a.w};
            float ab[4] = {a4b.x, a4b.y, a4b.z, a4b.w};
            #pragma unroll
            for (int c = 0; c < 4; c++) {
                int m = 4*mq + c;
                float4 e4 = *(const float4*)&se[m*132 + rq*4];
                e1.x += aa[c]*e4.x; e1.y += aa[c]*e4.y; e1.z += aa[c]*e4.z; e1.w += aa[c]*e4.w;
                e2.x += ab[c]*e4.x; e2.y += ab[c]*e4.y; e2.z += ab[c]*e4.z; e2.w += ab[c]*e4.w;
            }
        }
        *(float4*)&sew[hb*132 + rq*4]     = e1;
        *(float4*)&sew[(hb+4)*132 + rq*4] = e2;
    }
    __syncthreads();   // bar4 (se dead; sec may alias it)

    // ---- phase D: edge ctx (coalesced float4, K-split 8) + sctx finalize ----
    float* sec = se;   // 8*128 floats, aliases dead se
    float4 accE = make_float4(0.f,0.f,0.f,0.f);
    {
        int col4 = t & 31, rgrp = t >> 5;
        int h2 = col4 >> 2;
        const float* wqb = Wqkve + 128 + 4*col4;
        #pragma unroll 4
        for (int ri = 0; ri < 16; ri++) {
            int r = rgrp*16 + ri;
            float sv = sew[h2*132 + r];
            float4 w4 = *(const float4*)&wqb[(size_t)r*256];
            accE.x += sv*w4.x; accE.y += sv*w4.y; accE.z += sv*w4.z; accE.w += sv*w4.w;
        }
        if (t < 64) {
            // sctx finalize: this thread held half-0 partial for c4 = t
            float4 p = *(const float4*)&sq[t*4];
            float4 tot;
            tot.x = accS.x + p.x; tot.y = accS.y + p.y;
            tot.z = accS.z + p.z; tot.w = accS.w + p.w;
            *(float4*)&ws[OFF_HCAT + (size_t)n*384 + 4*t] = tot;
        }
        *(float4*)&sec[rgrp*128 + col4*4] = accE;
    }
    __syncthreads();   // bar5

    if (t < 128) {
        float ec = bqkve[128 + t];
        #pragma unroll
        for (int g2 = 0; g2 < 8; g2++) ec += sec[g2*128 + t];
        ws[OFF_HCAT + (size_t)n*384 + 256 + t] = ec;
    }
    if (t < 3) {
        const float* Vm = ws + OFF_VMAT + g*9;
        float gc = Vm[t*3+0]*sg3[0] + Vm[t*3+1]*sg3[1] + Vm[t*3+2]*sg3[2] + ws[OFF_CEN + g*3 + t];
        float gt = ws[OFF_GATE + n];
        out[OUT_GEO_OFF + (size_t)n*3 + t] = gc * gt + geo[(size_t)n*3 + t] * (1.0f - gt);
    }
}

// ---------------- Kernel 5: MLP — register-tiled fc1+gelu+LN+fc2+residual --
__global__ __launch_bounds__(256) void k_mlp(
    const float* __restrict__ tok, const float* __restrict__ Wfc1,
    const float* __restrict__ bfc1, const float* __restrict__ lnhg,
    const float* __restrict__ lnhb, const float* __restrict__ Wfc2,
    const float* __restrict__ bfc2, const float* __restrict__ ws,
    float* __restrict__ out)
{
    __shared__ __align__(16) float A[384 * 20];
    int t = threadIdx.x;
    int tok0 = blockIdx.x * 16;
    int i = t >> 6, j = t & 63;
    const float* hc = ws + OFF_HCAT;

    for (int it = 0; it < 24; it++) {
        int idx = it*256 + t;
        int tt = idx / 384;
        int k  = idx - tt*384;
        A[k*20 + tt] = hc[(size_t)tok0*384 + idx];
    }
    __syncthreads();

    float4 acc1[4];
    acc1[0] = acc1[1] = acc1[2] = acc1[3] = make_float4(0.f,0.f,0.f,0.f);
    {
        const float* wp = Wfc1 + 4*j;
        #pragma unroll 4
        for (int k = 0; k < 384; k++) {
            float4 a4 = *(const float4*)&A[k*20 + 4*i];
            float4 w4 = *(const float4*)&wp[(size_t)k*256];
            fma4x4(a4, w4, acc1);
        }
    }
    float h[4][4];
    {
        float4 b4 = *(const float4*)&bfc1[4*j];
        for (int ti = 0; ti < 4; ti++) {
            float xv[4] = {acc1[ti].x + b4.x, acc1[ti].y + b4.y, acc1[ti].z + b4.z, acc1[ti].w + b4.w};
            for (int c = 0; c < 4; c++) {
                float x = xv[c];
                h[ti][c] = 0.5f * x * (1.0f + erff(x * 0.70710678118654752f));
            }
        }
    }
    __syncthreads();

    {
        float s[4], q[4];
        for (int ti = 0; ti < 4; ti++) {
            s[ti] = h[ti][0] + h[ti][1] + h[ti][2] + h[ti][3];
            q[ti] = h[ti][0]*h[ti][0] + h[ti][1]*h[ti][1] + h[ti][2]*h[ti][2] + h[ti][3]*h[ti][3];
        }
        for (int m = 32; m >= 1; m >>= 1)
            for (int ti = 0; ti < 4; ti++) {
                s[ti] += __shfl_xor(s[ti], m, 64);
                q[ti] += __shfl_xor(q[ti], m, 64);
            }
        float4 g4 = *(const float4*)&lnhg[4*j];
        float4 b4 = *(const float4*)&lnhb[4*j];
        float gg[4] = {g4.x, g4.y, g4.z, g4.w};
        float bb[4] = {b4.x, b4.y, b4.z, b4.w};
        for (int ti = 0; ti < 4; ti++) {
            float mu = s[ti] * (1.0f/256.0f);
            float var = q[ti] * (1.0f/256.0f) - mu*mu;
            float rinv = rsqrtf(var + 1e-5f);
            for (int c = 0; c < 4; c++) {
                float hn = (h[ti][c] - mu) * rinv * gg[c] + bb[c];
                A[(4*j + c)*20 + 4*i + ti] = hn;
            }
        }
    }
    __syncthreads();

    float4 acc2[4];
    acc2[0] = acc2[1] = acc2[2] = acc2[3] = make_float4(0.f,0.f,0.f,0.f);
    {
        const float* wp = Wfc2 + 4*j;
        #pragma unroll 4
        for (int k = 0; k < 256; k++) {
            float4 a4 = *(const float4*)&A[k*20 + 4*i];
            float4 w4 = *(const float4*)&wp[(size_t)k*256];
            fma4x4(a4, w4, acc2);
        }
    }
    {
        float4 b4 = *(const float4*)&bfc2[4*j];
        for (int ti = 0; ti < 4; ti++) {
            size_t o = (size_t)(tok0 + 4*i + ti) * 256 + 4*j;
            float4 r4 = *(const float4*)&tok[o];
            float4 v;
            v.x = acc2[ti].x + b4.x + r4.x;
            v.y = acc2[ti].y + b4.y + r4.y;
            v.z = acc2[ti].z + b4.z + r4.z;
            v.w = acc2[ti].w + b4.w + r4.w;
            *(float4*)&out[o] = v;
        }
    }
}

extern "C" void kernel_launch(void* const* d_in, const int* in_sizes, int n_in,
                              void* d_out, int out_size, void* d_ws, size_t ws_size,
                              hipStream_t stream) {
    (void)in_sizes; (void)n_in; (void)out_size; (void)ws_size;
    const float* tok   = (const float*)d_in[0];
    const float* geo   = (const float*)d_in[1];
    const float* edge  = (const float*)d_in[2];
    const int*   nbr   = (const int*)d_in[3];
    const void*  maskp = d_in[5];
    const float* ln_qkv_g = (const float*)d_in[6];
    const float* ln_qkv_b = (const float*)d_in[7];
    const float* Wqkv  = (const float*)d_in[8];
    const float* bqkv  = (const float*)d_in[9];
    const float* ln_e_g = (const float*)d_in[10];
    const float* ln_e_b = (const float*)d_in[11];
    const float* Wqkve = (const float*)d_in[12];
    const float* bqkve = (const float*)d_in[13];
    const float* w_attn = (const float*)d_in[14];
    const float* w_edge = (const float*)d_in[15];
    const float* Wgate = (const float*)d_in[16];
    const float* bgate = (const float*)d_in[17];
    const float* Wfc1  = (const float*)d_in[18];
    const float* bfc1  = (const float*)d_in[19];
    const float* lnhg  = (const float*)d_in[20];
    const float* lnhb  = (const float*)d_in[21];
    const float* Wfc2  = (const float*)d_in[22];
    const float* bfc2  = (const float*)d_in[23];
    const float* Wfa   = (const float*)d_in[24];
    const float* bfa   = (const float*)d_in[25];
    float* ws  = (float*)d_ws;
    float* out = (float*)d_out;

    k_fold<<<dim3(279), dim3(256), 0, stream>>>(Wqkv, bqkv, Wqkve, bqkve, w_attn, w_edge,
                                                (const int*)maskp, ws);
    k_tokprep<<<dim3(512), dim3(320), 0, stream>>>(tok, ln_qkv_g, ln_qkv_b, Wgate, bgate, ws);
    k_geo<<<dim3(16), dim3(256), 0, stream>>>(geo, ws);
    k_attn<<<dim3(8192), dim3(256), 0, stream>>>(edge, nbr, maskp, ln_e_g, ln_e_b, bqkve,
                                                 Wqkve, Wfa, bfa, geo, ws, out);
    k_mlp<<<dim3(512), dim3(256), 0, stream>>>(tok, Wfc1, bfc1, lnhg, lnhb, Wfc2, bfc2, ws, out);
}

// Round 5
// 398.593 us; speedup vs baseline: 1.1760x; 1.0981x over previous
//
#include <hip/hip_runtime.h>
#include <math.h>

#define NTOK 8192
#define NPG  512
#define MNEI 32
#define DM   256
#define DE   128
#define NH   8

// workspace offsets (in floats)
#define OFF_WV    0u          // 256*256  [k][256] v-weights
#define OFF_WQAK  65536u      // 16*256   [c][k] qa/ka transposed
#define OFF_BCAT  69632u      // 272 (cols 0..15 qa/ka bias, 16..271 v bias)
#define OFF_WEF   69904u      // 8*128  [h][r]
#define OFF_BEF   70928u      // 8
#define OFF_FLAG  70936u      // 1 int
#define OFF_QA    70944u      // 8192*8
#define OFF_KA    136480u     // 8192*8
#define OFF_GATE  202016u     // 8192
#define OFF_VW    210208u     // 8192*256
#define OFF_PROJ  2307360u    // 8192*3
#define OFF_VMAT  2331936u    // 16*9
#define OFF_CEN   2332080u    // 16*3
#define OFF_HCAT  2332128u    // 8192*384

#define OUT_GEO_OFF 2097152   // 8192*256

__device__ __forceinline__ void fma4x4(const float4 a, const float4 w, float4* acc) {
    acc[0].x += a.x*w.x; acc[0].y += a.x*w.y; acc[0].z += a.x*w.z; acc[0].w += a.x*w.w;
    acc[1].x += a.y*w.x; acc[1].y += a.y*w.y; acc[1].z += a.y*w.z; acc[1].w += a.y*w.w;
    acc[2].x += a.z*w.x; acc[2].y += a.z*w.y; acc[2].z += a.z*w.z; acc[2].w += a.z*w.w;
    acc[3].x += a.w*w.x; acc[3].y += a.w*w.y; acc[3].z += a.w*w.z; acc[3].w += a.w*w.w;
}

__device__ __forceinline__ float dot4(const float4 a, const float4 b) {
    return a.x*b.x + a.y*b.y + a.z*b.z + a.w*b.w;
}

// ---------------- Kernel 1: weight folding + mask layout detection ----------
__global__ __launch_bounds__(256) void k_fold(
    const float* __restrict__ Wqkv, const float* __restrict__ bqkv,
    const float* __restrict__ Wqkve, const float* __restrict__ bqkve,
    const float* __restrict__ w_attn, const float* __restrict__ w_edge,
    const int* __restrict__ maskp, float* __restrict__ ws)
{
    int t = threadIdx.x;
    if (blockIdx.x == 0) {
        __shared__ int sbad, sflt;
        if (t == 0) { sbad = 0; sflt = 0; }
        __syncthreads();
        int bad = 0, flt = 0;
        for (int i = 0; i < 256; i++) {
            unsigned int w = (unsigned int)maskp[i*256 + t];
            if (w > 1u) bad = 1;
            if (w == 0x3F800000u) flt = 1;
        }
        if (bad) atomicOr(&sbad, 1);
        if (flt) atomicOr(&sflt, 1);
        __syncthreads();
        if (t == 0) {
            int f = sflt ? 2 : (sbad ? 1 : 0);
            ((int*)(ws + OFF_FLAG))[0] = f;
        }
        return;
    }
    int gid = (blockIdx.x - 1) * 256 + t;
    if (gid < 65536) {
        int k = gid >> 8, c = gid & 255;
        ws[OFF_WV + gid] = Wqkv[k*768 + 512 + c];
    } else if (gid < 69632) {
        int idx = gid - 65536;
        int c = idx >> 8, k = idx & 255;
        int h = c & 7; int off = (c < 8) ? 0 : 256;
        float s = 0.f;
        for (int d = 0; d < 32; d++) s += Wqkv[k*768 + off + h*32 + d] * w_attn[d];
        ws[OFF_WQAK + idx] = s;
    } else if (gid < 69632 + 272) {
        int c = gid - 69632;
        float val;
        if (c < 16) {
            int h = c & 7; int off = (c < 8) ? 0 : 256;
            float s = 0.f;
            for (int d = 0; d < 32; d++) s += bqkv[off + h*32 + d] * w_attn[d];
            val = s;
        } else {
            val = bqkv[512 + (c - 16)];
        }
        ws[OFF_BCAT + c] = val;
    } else if (gid < 69904 + 1024) {
        int i = gid - 69904;
        int h = i >> 7, r = i & 127;
        float s = 0.f;
        for (int e = 0; e < 16; e++) s += Wqkve[r*256 + h*16 + e] * w_edge[e];
        ws[OFF_WEF + i] = s;
    } else if (gid < 70928 + 8) {
        int h = gid - 70928;
        float s = 0.f;
        for (int e = 0; e < 16; e++) s += bqkve[h*16 + e] * w_edge[e];
        ws[OFF_BEF + h] = s;
    }
}

// ---------------- Kernel 2: token LN + gate + [qa|ka|v] ---------------------
// 8 tokens/block, 1024 blocks, 256 threads. Waves 0-1: v-GEMM (i=wave,
// j=lane, per k: 1 broadcast LDS b128 + 1 coalesced global b128 + 16 FMA).
// Waves 2-3: qa/ka via transposed WQAK (contiguous float4 weight reads).
__global__ __launch_bounds__(256) void k_tokprep(
    const float* __restrict__ tok, const float* __restrict__ ln_g,
    const float* __restrict__ ln_b, const float* __restrict__ Wgate,
    const float* __restrict__ bgate, float* __restrict__ ws)
{
    __shared__ __align__(16) float sln[256 * 12];   // [k][8 tokens + pad]
    int t = threadIdx.x;
    int tok0 = blockIdx.x * 8;

    #pragma unroll
    for (int q = 0; q < 8; q++)
        sln[t*12 + q] = tok[(size_t)(tok0 + q) * 256 + t];
    __syncthreads();

    int wave = t >> 6, lane = t & 63;
    for (int rr = 0; rr < 2; rr++) {
        int tt = wave * 2 + rr;
        float s = 0.f, gdot = 0.f;
        float xs[4];
        #pragma unroll
        for (int q = 0; q < 4; q++) {
            int k = lane + 64*q;
            float x = sln[k*12 + tt];
            xs[q] = x; s += x; gdot += x * Wgate[k];
        }
        for (int m = 32; m >= 1; m >>= 1) { s += __shfl_xor(s,m,64); gdot += __shfl_xor(gdot,m,64); }
        float mu = s * (1.0f/256.0f);
        float vs = 0.f;
        #pragma unroll
        for (int q = 0; q < 4; q++) { float d = xs[q]-mu; vs += d*d; }
        for (int m = 32; m >= 1; m >>= 1) vs += __shfl_xor(vs,m,64);
        float rinv = rsqrtf(vs*(1.0f/256.0f)+1e-5f);
        #pragma unroll
        for (int q = 0; q < 4; q++) {
            int k = lane + 64*q;
            sln[k*12 + tt] = (xs[q]-mu)*rinv*ln_g[k] + ln_b[k];
        }
        if (lane == 0) ws[OFF_GATE + tok0 + tt] = 1.0f/(1.0f+expf(-(gdot + bgate[0])));
    }
    __syncthreads();

    if (t < 128) {
        int i = t >> 6, j = t & 63;          // tokens 4i..4i+3, v-cols 4j..4j+3
        const float* Wc = ws + OFF_WV + 4*j;
        float4 acc[4];
        acc[0] = acc[1] = acc[2] = acc[3] = make_float4(0.f,0.f,0.f,0.f);
        #pragma unroll 8
        for (int k = 0; k < 256; k++) {
            float4 a4 = *(const float4*)&sln[k*12 + 4*i];
            float4 w4 = *(const float4*)&Wc[(size_t)k*256];
            fma4x4(a4, w4, acc);
        }
        float4 b4 = *(const float4*)&ws[OFF_BCAT + 16 + 4*j];
        #pragma unroll
        for (int ti = 0; ti < 4; ti++) {
            int n = tok0 + 4*i + ti;
            float4 v = acc[ti];
            v.x += b4.x; v.y += b4.y; v.z += b4.z; v.w += b4.w;
            *(float4*)&ws[OFF_VW + (size_t)n*256 + 4*j] = v;
        }
    } else {
        int wave3 = (t >> 6) - 2;            // 0 or 1
        int col = t & 15, tp = (t & 63) >> 4;
        int tokn = wave3*4 + tp;
        const float* wq = ws + OFF_WQAK + col*256;
        float acc = 0.f;
        #pragma unroll 8
        for (int k4 = 0; k4 < 64; k4++) {
            float4 w4 = *(const float4*)&wq[4*k4];
            acc += w4.x * sln[(4*k4+0)*12 + tokn]
                 + w4.y * sln[(4*k4+1)*12 + tokn]
                 + w4.z * sln[(4*k4+2)*12 + tokn]
                 + w4.w * sln[(4*k4+3)*12 + tokn];
        }
        acc += ws[OFF_BCAT + col];
        int n = tok0 + tokn;
        if (col < 8) ws[OFF_QA + n*8 + col] = acc;
        else         ws[OFF_KA + n*8 + (col - 8)] = acc;
    }
}

// ---------------- Kernel 3: per-graph geometry (center, cov, eigh, proj) ----
__global__ __launch_bounds__(256) void k_geo(const float* __restrict__ geo, float* __restrict__ ws)
{
    __shared__ float sred[4 * 9];
    __shared__ float sres[9];
    __shared__ float sV[9];
    int t = threadIdx.x, g = blockIdx.x;
    int wave = t >> 6, lane = t & 63;
    const float* gp = geo + (size_t)g * NPG * 3;

    float x0[2], y0[2], z0[2];
    float sx = 0.f, sy = 0.f, sz = 0.f;
    for (int i = 0; i < 2; i++) {
        int p = t + 256 * i;
        x0[i] = gp[p*3 + 0]; y0[i] = gp[p*3 + 1]; z0[i] = gp[p*3 + 2];
        sx += x0[i]; sy += y0[i]; sz += z0[i];
    }
    {
        float vals[3] = {sx, sy, sz};
        for (int q = 0; q < 3; q++) {
            float v = vals[q];
            for (int m = 32; m >= 1; m >>= 1) v += __shfl_xor(v, m, 64);
            if (lane == 0) sred[wave*9 + q] = v;
        }
    }
    __syncthreads();
    if (t < 3) {
        float s = 0.f;
        for (int w = 0; w < 4; w++) s += sred[w*9 + t];
        sres[t] = s * (1.0f / 512.0f);
    }
    __syncthreads();
    float cx = sres[0], cy = sres[1], cz = sres[2];

    float c6[6] = {0.f, 0.f, 0.f, 0.f, 0.f, 0.f};
    for (int i = 0; i < 2; i++) {
        float dx = x0[i] - cx, dy = y0[i] - cy, dz = z0[i] - cz;
        c6[0] += dx*dx; c6[1] += dx*dy; c6[2] += dx*dz;
        c6[3] += dy*dy; c6[4] += dy*dz; c6[5] += dz*dz;
    }
    for (int q = 0; q < 6; q++) {
        float v = c6[q];
        for (int m = 32; m >= 1; m >>= 1) v += __shfl_xor(v, m, 64);
        if (lane == 0) sred[wave*9 + q] = v;
    }
    __syncthreads();
    if (t < 6) {
        float s = 0.f;
        for (int w = 0; w < 4; w++) s += sred[w*9 + t];
        sres[t] = s;
    }
    __syncthreads();

    if (t == 0) {
        double a[3][3];
        a[0][0] = sres[0]; a[0][1] = a[1][0] = sres[1]; a[0][2] = a[2][0] = sres[2];
        a[1][1] = sres[3]; a[1][2] = a[2][1] = sres[4]; a[2][2] = sres[5];
        double v[3][3] = {{1,0,0},{0,1,0},{0,0,1}};
        const int ps[3] = {0, 0, 1}, qs[3] = {1, 2, 2};
        for (int sweep = 0; sweep < 10; sweep++) {
            for (int pi = 0; pi < 3; pi++) {
                int p = ps[pi], q = qs[pi];
                double apq = a[p][q];
                if (fabs(apq) < 1e-300) continue;
                double theta = (a[q][q] - a[p][p]) / (2.0 * apq);
                double tt = ((theta >= 0.0) ? 1.0 : -1.0) / (fabs(theta) + sqrt(theta*theta + 1.0));
                double c = 1.0 / sqrt(tt*tt + 1.0), s = tt * c;
                int k = 3 - p - q;
                double app = a[p][p], aqq = a[q][q], akp = a[k][p], akq = a[k][q];
                a[p][p] = app - tt * apq;
                a[q][q] = aqq + tt * apq;
                a[p][q] = 0.0; a[q][p] = 0.0;
                a[k][p] = c*akp - s*akq; a[p][k] = a[k][p];
                a[k][q] = s*akp + c*akq; a[q][k] = a[k][q];
                for (int kk = 0; kk < 3; kk++) {
                    double vp = v[kk][p], vq = v[kk][q];
                    v[kk][p] = c*vp - s*vq;
                    v[kk][q] = s*vp + c*vq;
                }
            }
        }
        for (int r = 0; r < 3; r++)
            for (int c2 = 0; c2 < 3; c2++) {
                float fv = (float)v[r][c2];
                sV[r*3 + c2] = fv;
                ws[OFF_VMAT + g*9 + r*3 + c2] = fv;
            }
        ws[OFF_CEN + g*3 + 0] = cx;
        ws[OFF_CEN + g*3 + 1] = cy;
        ws[OFF_CEN + g*3 + 2] = cz;
    }
    __syncthreads();

    for (int i = 0; i < 2; i++) {
        int p = t + 256 * i;
        float dx = x0[i] - cx, dy = y0[i] - cy, dz = z0[i] - cz;
        for (int c = 0; c < 3; c++) {
            float pr = dx * sV[0*3 + c] + dy * sV[1*3 + c] + dz * sV[2*3 + c];
            ws[OFF_PROJ + (size_t)(g*NPG + p)*3 + c] = pr;
        }
    }
}

// ---------------- Kernel 4: fused per-token attention ----------------------
// Logits from registers (thread (m,sub) keeps its 16 LN'd floats) against
// sub-major weights (conflict-free b128 broadcast) + 8-lane butterfly.
// LDS ~27.1 KB -> 6 blocks/CU. 5 barriers.
__global__ __launch_bounds__(256) void k_attn(
    const float* __restrict__ edge, const int* __restrict__ nbr,
    const void* __restrict__ maskp,
    const float* __restrict__ lneg, const float* __restrict__ lneb,
    const float* __restrict__ bqkve, const float* __restrict__ Wqkve,
    const float* __restrict__ Wfa, const float* __restrict__ bfa,
    const float* __restrict__ geo, float* __restrict__ ws, float* __restrict__ out)
{
    __shared__ __align__(16) float se[32 * 132];    // LN rows; sec aliases in phase D
    __shared__ __align__(16) float uSWE[8 * 132];   // [sub][h][16] logit w; sq aliases after logits
    __shared__ __align__(16) float sew[8 * 132];    // attn-weighted rows
    __shared__ __align__(16) float sattn[8 * 36];   // logits -> attn (in place)
    __shared__ int   snbr[32];
    __shared__ int   smask[32];
    __shared__ float sqa[8], sbef[8];
    __shared__ float sg3[4];

    int t = threadIdx.x;
    int n = blockIdx.x;
    int g = n >> 9;
    int flag = ((const int*)(ws + OFF_FLAG))[0];

    // ---- phase 1: stage ----
    if (t < 32) {
        snbr[t] = nbr[n*32 + t];
        int mv;
        if (flag == 1)      mv = (int)((const unsigned char*)maskp)[n*32 + t];
        else if (flag == 2) mv = (((const float*)maskp)[n*32 + t] != 0.0f) ? 1 : 0;
        else                mv = ((const int*)maskp)[n*32 + t];
        smask[t] = mv;
    }
    if (t < 8) { sqa[t] = ws[OFF_QA + n*8 + t]; sbef[t] = ws[OFF_BEF + t]; }
    {
        // logit weights, re-laid out sub-major: uSWE[sub*132 + h*16 + c]
        int idx = t * 4;
        int h = idx >> 7, r = idx & 127;
        int sub = r >> 4, c = r & 15;
        *(float4*)&uSWE[sub*132 + h*16 + c] = *(const float4*)&ws[OFF_WEF + idx];
    }
    {
        const float4* ep = (const float4*)(edge + (size_t)n * 4096);
        #pragma unroll
        for (int j = 0; j < 4; j++) {
            int l = j*1024 + t*4;
            float4 v4 = ep[l >> 2];
            int m = l >> 7, r = l & 127;
            *(float4*)&se[m*132 + r] = v4;
        }
    }
    __syncthreads();   // bar1

    // ---- phase 2: edge-row layernorm (8 threads/row) + logits in registers -
    int m = t >> 3, sub = t & 7;
    {
        int base = m*132 + sub*16;
        float4 x0 = *(float4*)&se[base + 0];
        float4 x1 = *(float4*)&se[base + 4];
        float4 x2 = *(float4*)&se[base + 8];
        float4 x3 = *(float4*)&se[base + 12];
        float s = x0.x+x0.y+x0.z+x0.w + x1.x+x1.y+x1.z+x1.w
                + x2.x+x2.y+x2.z+x2.w + x3.x+x3.y+x3.z+x3.w;
        for (int mm = 4; mm >= 1; mm >>= 1) s += __shfl_xor(s, mm, 8);
        float mu = s * (1.0f / 128.0f);
        float vs = (x0.x-mu)*(x0.x-mu) + (x0.y-mu)*(x0.y-mu) + (x0.z-mu)*(x0.z-mu) + (x0.w-mu)*(x0.w-mu)
                 + (x1.x-mu)*(x1.x-mu) + (x1.y-mu)*(x1.y-mu) + (x1.z-mu)*(x1.z-mu) + (x1.w-mu)*(x1.w-mu)
                 + (x2.x-mu)*(x2.x-mu) + (x2.y-mu)*(x2.y-mu) + (x2.z-mu)*(x2.z-mu) + (x2.w-mu)*(x2.w-mu)
                 + (x3.x-mu)*(x3.x-mu) + (x3.y-mu)*(x3.y-mu) + (x3.z-mu)*(x3.z-mu) + (x3.w-mu)*(x3.w-mu);
        for (int mm = 4; mm >= 1; mm >>= 1) vs += __shfl_xor(vs, mm, 8);
        float rinv = rsqrtf(vs * (1.0f / 128.0f) + 1e-5f);
        const float4* gp4 = (const float4*)(lneg + sub*16);
        const float4* bp4 = (const float4*)(lneb + sub*16);
        float4 g0 = gp4[0], g1 = gp4[1], g2 = gp4[2], g3 = gp4[3];
        float4 b0 = bp4[0], b1 = bp4[1], b2 = bp4[2], b3 = bp4[3];
        x0.x=(x0.x-mu)*rinv*g0.x+b0.x; x0.y=(x0.y-mu)*rinv*g0.y+b0.y;
        x0.z=(x0.z-mu)*rinv*g0.z+b0.z; x0.w=(x0.w-mu)*rinv*g0.w+b0.w;
        x1.x=(x1.x-mu)*rinv*g1.x+b1.x; x1.y=(x1.y-mu)*rinv*g1.y+b1.y;
        x1.z=(x1.z-mu)*rinv*g1.z+b1.z; x1.w=(x1.w-mu)*rinv*g1.w+b1.w;
        x2.x=(x2.x-mu)*rinv*g2.x+b2.x; x2.y=(x2.y-mu)*rinv*g2.y+b2.y;
        x2.z=(x2.z-mu)*rinv*g2.z+b2.z; x2.w=(x2.w-mu)*rinv*g2.w+b2.w;
        x3.x=(x3.x-mu)*rinv*g3.x+b3.x; x3.y=(x3.y-mu)*rinv*g3.y+b3.y;
        x3.z=(x3.z-mu)*rinv*g3.z+b3.z; x3.w=(x3.w-mu)*rinv*g3.w+b3.w;
        *(float4*)&se[base + 0]  = x0;
        *(float4*)&se[base + 4]  = x1;
        *(float4*)&se[base + 8]  = x2;
        *(float4*)&se[base + 12] = x3;

        // logits: all-head partials vs own 16 registers
        float accl[8];
        const float* wb = &uSWE[sub*132];
        #pragma unroll
        for (int h = 0; h < 8; h++) {
            const float4* wp = (const float4*)(wb + h*16);
            accl[h] = dot4(x0,wp[0]) + dot4(x1,wp[1]) + dot4(x2,wp[2]) + dot4(x3,wp[3]);
        }
        #pragma unroll
        for (int st = 1; st < 8; st <<= 1) {
            #pragma unroll
            for (int h = 0; h < 8; h++) accl[h] += __shfl_xor(accl[h], st, 8);
        }
        float myacc = accl[0];
        #pragma unroll
        for (int h = 1; h < 8; h++) myacc = (sub == h) ? accl[h] : myacc;
        float lg = sqa[sub] + sbef[sub] + myacc + ws[OFF_KA + snbr[m]*8 + sub];
        if (!smask[m]) lg = -1e9f;
        sattn[sub*36 + m] = lg;
    }
    __syncthreads();   // bar2

    // ---- phase 3: softmax over m per h (in place) ----
    {
        int h = t >> 5, m2 = t & 31;
        float x = sattn[h*36 + m2];
        float mx = x;
        for (int mm = 16; mm >= 1; mm >>= 1) mx = fmaxf(mx, __shfl_xor(mx, mm, 32));
        float e = expf(x - mx);
        float sum = e;
        for (int mm = 16; mm >= 1; mm >>= 1) sum += __shfl_xor(sum, mm, 32);
        sattn[h*36 + m2] = e / sum;
    }
    __syncthreads();   // bar3 (uSWE dead -> sq aliases it)

    float* sq = uSWE;   // 64*4 floats, aliases dead logit weights

    // ---- phase C: wave-specialized ----
    float4 accS = make_float4(0.f,0.f,0.f,0.f);
    if (t < 128) {
        int half = t >> 6, c4 = t & 63;
        int h = c4 >> 3;
        const float* vw = ws + OFF_VW;
        #pragma unroll 4
        for (int mi = 0; mi < 16; mi++) {
            int mm2 = half*16 + mi;
            float a = sattn[h*36 + mm2];
            int row = snbr[mm2];
            float4 v4 = *(const float4*)&vw[(size_t)row*256 + 4*c4];
            accS.x += a*v4.x; accS.y += a*v4.y; accS.z += a*v4.z; accS.w += a*v4.w;
        }
        if (half) *(float4*)&sq[c4*4] = accS;
        if (t < 32) {
            float wmv = 0.f;
            #pragma unroll
            for (int h2 = 0; h2 < 8; h2++) wmv += Wfa[h2] * sattn[h2*36 + t];
            int row = snbr[t];
            const float* pp = ws + OFF_PROJ + (size_t)row*3;
            float q0 = wmv * pp[0], q1 = wmv * pp[1], q2 = wmv * pp[2];
            for (int st = 16; st >= 1; st >>= 1) {
                q0 += __shfl_xor(q0, st, 32);
                q1 += __shfl_xor(q1, st, 32);
                q2 += __shfl_xor(q2, st, 32);
            }
            if (t < 3) {
                float sd = (t == 0) ? q0 : (t == 1) ? q1 : q2;
                float bb = bfa[0];
                float p1 = sd + bb, p2 = -sd + bb;
                float s1v = p1 / (1.0f + expf(-p1));
                float s2v = p2 / (1.0f + expf(-p2));
                sg3[t] = 0.5f * (s1v - s2v);
            }
        }
    } else {
        int rq = t & 31, hb = (t >> 5) - 4;
        float4 e1 = make_float4(0.f,0.f,0.f,0.f);
        float4 e2 = make_float4(0.f,0.f,0.f,0.f);
        #pragma unroll
        for (int mq = 0; mq < 8; mq++) {
            float4 a4a = *(const float4*)&sattn[hb*36 + 4*mq];
            float4 a4b = *(const float4*)&sattn[(hb+4)*36 + 4*mq];
            float aa[4] = {a4a.x, a4a.y, a4a.z, a4a.w};
            float ab[4] = {a4b.x, a4b.y, a4b.z, a4b.w};
            #pragma unroll
            for (int c = 0; c < 4; c++) {
                int mm2 = 4*mq + c;
                float4 e4 = *(const float4*)&se[mm2*132 + rq*4];
                e1.x += aa[c]*e4.x; e1.y += aa[c]*e4.y; e1.z += aa[c]*e4.z; e1.w += aa[c]*e4.w;
                e2.x += ab[c]*e4.x; e2.y += ab[c]*e4.y; e2.z += ab[c]*e4.z; e2.w += ab[c]*e4.w;
            }
        }
        *(float4*)&sew[hb*132 + rq*4]     = e1;
        *(float4*)&sew[(hb+4)*132 + rq*4] = e2;
    }
    __syncthreads();   // bar4 (se dead; sec aliases it)

    // ---- phase D: edge ctx (coalesced float4, K-split 8) + sctx finalize ----
    float* sec = se;
    float4 accE = make_float4(0.f,0.f,0.f,0.f);
    {
        int col4 = t & 31, rgrp = t >> 5;
        int h2 = col4 >> 2;
        const float* wqb = Wqkve + 128 + 4*col4;
        #pragma unroll 4
        for (int ri = 0; ri < 16; ri++) {
            int r = rgrp*16 + ri;
            float sv = sew[h2*132 + r];
            float4 w4 = *(const float4*)&wqb[(size_t)r*256];
            accE.x += sv*w4.x; accE.y += sv*w4.y; accE.z += sv*w4.z; accE.w += sv*w4.w;
        }
        if (t < 64) {
            float4 p = *(const float4*)&sq[t*4];
            float4 tot;
            tot.x = accS.x + p.x; tot.y = accS.y + p.y;
            tot.z = accS.z + p.z; tot.w = accS.w + p.w;
            *(float4*)&ws[OFF_HCAT + (size_t)n*384 + 4*t] = tot;
        }
        *(float4*)&sec[rgrp*128 + col4*4] = accE;
    }
    __syncthreads();   // bar5

    if (t < 128) {
        float ec = bqkve[128 + t];
        #pragma unroll
        for (int g2 = 0; g2 < 8; g2++) ec += sec[g2*128 + t];
        ws[OFF_HCAT + (size_t)n*384 + 256 + t] = ec;
    }
    if (t < 3) {
        const float* Vm = ws + OFF_VMAT + g*9;
        float gc = Vm[t*3+0]*sg3[0] + Vm[t*3+1]*sg3[1] + Vm[t*3+2]*sg3[2] + ws[OFF_CEN + g*3 + t];
        float gt = ws[OFF_GATE + n];
        out[OUT_GEO_OFF + (size_t)n*3 + t] = gc * gt + geo[(size_t)n*3 + t] * (1.0f - gt);
    }
}

// ---------------- Kernel 5: MLP — 8 tokens/block, K-split halves -----------
// 1024 blocks x 256 threads: i2=(t>>6)&1 token-group, kh=t>>7 K-half,
// j=t&63 col-group. LDS reduce between halves.
__global__ __launch_bounds__(256) void k_mlp(
    const float* __restrict__ tok, const float* __restrict__ Wfc1,
    const float* __restrict__ bfc1, const float* __restrict__ lnhg,
    const float* __restrict__ lnhb, const float* __restrict__ Wfc2,
    const float* __restrict__ bfc2, const float* __restrict__ ws,
    float* __restrict__ out)
{
    __shared__ __align__(16) float A[384 * 12];   // [k][8 tokens + pad]
    __shared__ __align__(16) float R[128 * 16];   // cross-half reduce
    int t = threadIdx.x;
    int tok0 = blockIdx.x * 8;
    int i2 = (t >> 6) & 1, kh = t >> 7, j = t & 63;
    const float* hc = ws + OFF_HCAT;

    #pragma unroll
    for (int q = 0; q < 12; q++) {
        int idx = q*256 + t;
        int tt = idx / 384;
        int k  = idx - tt*384;
        A[k*12 + tt] = hc[(size_t)tok0*384 + idx];
    }
    __syncthreads();

    // fc1 (half K per thread)
    float4 acc1[4];
    acc1[0] = acc1[1] = acc1[2] = acc1[3] = make_float4(0.f,0.f,0.f,0.f);
    {
        const float* wp = Wfc1 + 4*j;
        int kbase = kh * 192;
        #pragma unroll 8
        for (int kk = 0; kk < 192; kk++) {
            int k = kbase + kk;
            float4 a4 = *(const float4*)&A[k*12 + 4*i2];
            float4 w4 = *(const float4*)&wp[(size_t)k*256];
            fma4x4(a4, w4, acc1);
        }
    }
    if (kh == 1) {
        int rowid = t - 128;
        #pragma unroll
        for (int ti = 0; ti < 4; ti++) *(float4*)&R[rowid*16 + ti*4] = acc1[ti];
    }
    __syncthreads();

    float h[4][4];
    if (kh == 0) {
        float4 b4 = *(const float4*)&bfc1[4*j];
        #pragma unroll
        for (int ti = 0; ti < 4; ti++) {
            float4 p = *(const float4*)&R[t*16 + ti*4];
            float xv[4] = {acc1[ti].x + p.x + b4.x, acc1[ti].y + p.y + b4.y,
                           acc1[ti].z + p.z + b4.z, acc1[ti].w + p.w + b4.w};
            #pragma unroll
            for (int c = 0; c < 4; c++) {
                float x = xv[c];
                h[ti][c] = 0.5f * x * (1.0f + erff(x * 0.70710678118654752f));
            }
        }
        // LN across the 64 j-lanes (wave i2 shares tokens 4i2..4i2+3)
        float s[4], qv[4];
        #pragma unroll
        for (int ti = 0; ti < 4; ti++) {
            s[ti]  = h[ti][0] + h[ti][1] + h[ti][2] + h[ti][3];
            qv[ti] = h[ti][0]*h[ti][0] + h[ti][1]*h[ti][1] + h[ti][2]*h[ti][2] + h[ti][3]*h[ti][3];
        }
        for (int m = 32; m >= 1; m >>= 1)
            #pragma unroll
            for (int ti = 0; ti < 4; ti++) {
                s[ti]  += __shfl_xor(s[ti], m, 64);
                qv[ti] += __shfl_xor(qv[ti], m, 64);
            }
        float4 g4 = *(const float4*)&lnhg[4*j];
        float4 b42 = *(const float4*)&lnhb[4*j];
        float gg[4] = {g4.x, g4.y, g4.z, g4.w};
        float bb[4] = {b42.x, b42.y, b42.z, b42.w};
        #pragma unroll
        for (int ti = 0; ti < 4; ti++) {
            float mu = s[ti] * (1.0f/256.0f);
            float var = qv[ti] * (1.0f/256.0f) - mu*mu;
            float rinv = rsqrtf(var + 1e-5f);
            #pragma unroll
            for (int c = 0; c < 4; c++) {
                float hn = (h[ti][c] - mu) * rinv * gg[c] + bb[c];
                A[(4*j + c)*12 + 4*i2 + ti] = hn;
            }
        }
    }
    __syncthreads();

    // fc2 (half K per thread)
    float4 acc2[4];
    acc2[0] = acc2[1] = acc2[2] = acc2[3] = make_float4(0.f,0.f,0.f,0.f);
    {
        const float* wp = Wfc2 + 4*j;
        int kbase = kh * 128;
        #pragma unroll 8
        for (int kk = 0; kk < 128; kk++) {
            int k = kbase + kk;
            float4 a4 = *(const float4*)&A[k*12 + 4*i2];
            float4 w4 = *(const float4*)&wp[(size_t)k*256];
            fma4x4(a4, w4, acc2);
        }
    }
    if (kh == 1) {
        int rowid = t - 128;
        #pragma unroll
        for (int ti = 0; ti < 4; ti++) *(float4*)&R[rowid*16 + ti*4] = acc2[ti];
    }
    __syncthreads();

    if (kh == 0) {
        float4 b4 = *(const float4*)&bfc2[4*j];
        #pragma unroll
        for (int ti = 0; ti < 4; ti++) {
            float4 p = *(const float4*)&R[t*16 + ti*4];
            size_t o = (size_t)(tok0 + 4*i2 + ti) * 256 + 4*j;
            float4 r4 = *(const float4*)&tok[o];
            float4 v;
            v.x = acc2[ti].x + p.x + b4.x + r4.x;
            v.y = acc2[ti].y + p.y + b4.y + r4.y;
            v.z = acc2[ti].z + p.z + b4.z + r4.z;
            v.w = acc2[ti].w + p.w + b4.w + r4.w;
            *(float4*)&out[o] = v;
        }
    }
}

extern "C" void kernel_launch(void* const* d_in, const int* in_sizes, int n_in,
                              void* d_out, int out_size, void* d_ws, size_t ws_size,
                              hipStream_t stream) {
    (void)in_sizes; (void)n_in; (void)out_size; (void)ws_size;
    const float* tok   = (const float*)d_in[0];
    const float* geo   = (const float*)d_in[1];
    const float* edge  = (const float*)d_in[2];
    const int*   nbr   = (const int*)d_in[3];
    const void*  maskp = d_in[5];
    const float* ln_qkv_g = (const float*)d_in[6];
    const float* ln_qkv_b = (const float*)d_in[7];
    const float* Wqkv  = (const float*)d_in[8];
    const float* bqkv  = (const float*)d_in[9];
    const float* ln_e_g = (const float*)d_in[10];
    const float* ln_e_b = (const float*)d_in[11];
    const float* Wqkve = (const float*)d_in[12];
    const float* bqkve = (const float*)d_in[13];
    const float* w_attn = (const float*)d_in[14];
    const float* w_edge = (const float*)d_in[15];
    const float* Wgate = (const float*)d_in[16];
    const float* bgate = (const float*)d_in[17];
    const float* Wfc1  = (const float*)d_in[18];
    const float* bfc1  = (const float*)d_in[19];
    const float* lnhg  = (const float*)d_in[20];
    const float* lnhb  = (const float*)d_in[21];
    const float* Wfc2  = (const float*)d_in[22];
    const float* bfc2  = (const float*)d_in[23];
    const float* Wfa   = (const float*)d_in[24];
    const float* bfa   = (const float*)d_in[25];
    float* ws  = (float*)d_ws;
    float* out = (float*)d_out;

    k_fold<<<dim3(279), dim3(256), 0, stream>>>(Wqkv, bqkv, Wqkve, bqkve, w_attn, w_edge,
                                                (const int*)maskp, ws);
    k_tokprep<<<dim3(1024), dim3(256), 0, stream>>>(tok, ln_qkv_g, ln_qkv_b, Wgate, bgate, ws);
    k_geo<<<dim3(16), dim3(256), 0, stream>>>(geo, ws);
    k_attn<<<dim3(8192), dim3(256), 0, stream>>>(edge, nbr, maskp, ln_e_g, ln_e_b, bqkve,
                                                 Wqkve, Wfa, bfa, geo, ws, out);
    k_mlp<<<dim3(1024), dim3(256), 0, stream>>>(tok, Wfc1, bfc1, lnhg, lnhb, Wfc2, bfc2, ws, out);
}